// Round 1
// baseline (895.684 us; speedup 1.0000x reference)
//
#include <hip/hip_runtime.h>
#include <math.h>

// RoutingLayer: N=50000 rows, M=32 neighbors, D=128 dims = K=8 capsules x 16,
// 6 routing iterations. One wave (64 lanes) per row:
//   lane = k*8 + j  -> handles dims (2j, 2j+1) of capsule k
//   dot-reduce over capsule dims: shfl_xor 1,2,4 (within 8-lane group)
//   softmax over k:               shfl_xor 8,16,32 (stride-8 lanes)
// z (32 neighbors x 2 floats) lives in registers. No LDS, no barriers.

constexpr int NROWS = 50000;
constexpr int MN = 32;
constexpr int DDIM = 128;
constexpr int KC = 8;
constexpr float FEPS = 1e-12f;

__global__ __launch_bounds__(256) void capsule_norm_kernel(const float* __restrict__ x,
                                                           float* __restrict__ inv) {
    int c = blockIdx.x * 256 + threadIdx.x;  // capsule id = n*8 + k
    if (c >= NROWS * KC) return;
    const float4* p = reinterpret_cast<const float4*>(x) + (size_t)c * 4;  // 16 floats
    float ss = 0.f;
#pragma unroll
    for (int i = 0; i < 4; ++i) {
        float4 v = p[i];
        ss += v.x * v.x + v.y * v.y + v.z * v.z + v.w * v.w;
    }
    inv[c] = 1.0f / fmaxf(sqrtf(ss), FEPS);
}

template <bool USE_INV>
__global__ __launch_bounds__(256) void routing_kernel(const float* __restrict__ x,
                                                      const int* __restrict__ nbr,
                                                      const float* __restrict__ inv,
                                                      float* __restrict__ out) {
    const int lane = threadIdx.x & 63;
    const int n = blockIdx.x * 4 + (threadIdx.x >> 6);  // 12500*4 = 50000 exactly
    const int k = lane >> 3;

    // ---- own row, per-capsule normalized ----
    float2 xv = *reinterpret_cast<const float2*>(x + (size_t)n * DDIM + 2 * lane);
    float xc0, xc1;
    {
        float iv;
        if (USE_INV) {
            iv = inv[n * KC + k];
        } else {
            float ss = xv.x * xv.x + xv.y * xv.y;
            ss += __shfl_xor(ss, 1); ss += __shfl_xor(ss, 2); ss += __shfl_xor(ss, 4);
            iv = 1.0f / fmaxf(sqrtf(ss), FEPS);
        }
        xc0 = xv.x * iv;
        xc1 = xv.y * iv;
    }

    // ---- gather normalized neighbor rows into registers ----
    float z0[MN], z1[MN];
    const int* __restrict__ nrow = nbr + (size_t)n * MN;
#pragma unroll
    for (int m = 0; m < MN; ++m) {
        int idx = nrow[m];  // wave-uniform
        float2 v;
        if (idx < NROWS) {
            v = *reinterpret_cast<const float2*>(x + (size_t)idx * DDIM + 2 * lane);
        } else {
            v.x = 0.f; v.y = 0.f;  // padding row
        }
        float iv;
        if (USE_INV) {
            iv = (idx < NROWS) ? inv[idx * KC + k] : 1.0f;
        } else {
            float ss = v.x * v.x + v.y * v.y;
            ss += __shfl_xor(ss, 1); ss += __shfl_xor(ss, 2); ss += __shfl_xor(ss, 4);
            iv = 1.0f / fmaxf(sqrtf(ss), FEPS);
        }
        z0[m] = v.x * iv;
        z1[m] = v.y * iv;
    }

    // ---- iteration 0: p uniform = 1/8 ----
    float u0, u1;
    {
        float a0 = 0.f, a1 = 0.f;
#pragma unroll
        for (int m = 0; m < MN; ++m) { a0 += z0[m]; a1 += z1[m]; }
        u0 = xc0 + 0.125f * a0;
        u1 = xc1 + 0.125f * a1;
        float ss = u0 * u0 + u1 * u1;
        ss += __shfl_xor(ss, 1); ss += __shfl_xor(ss, 2); ss += __shfl_xor(ss, 4);
        float s = 1.0f / fmaxf(sqrtf(ss), FEPS);
        u0 *= s; u1 *= s;
    }

    // ---- iterations 1..5 ----
#pragma unroll 1
    for (int it = 1; it < 6; ++it) {
        float a0 = xc0, a1 = xc1;
#pragma unroll
        for (int m = 0; m < MN; ++m) {
            // p_raw[m][k] = sum_d z[m][k][d] * u[k][d]
            float p = z0[m] * u0 + z1[m] * u1;
            p += __shfl_xor(p, 1); p += __shfl_xor(p, 2); p += __shfl_xor(p, 4);
            // softmax over k (stride-8 lanes hold the 8 capsules)
            float mx = fmaxf(p, __shfl_xor(p, 8));
            mx = fmaxf(mx, __shfl_xor(mx, 16));
            mx = fmaxf(mx, __shfl_xor(mx, 32));
            float e = __expf(p - mx);
            float s = e + __shfl_xor(e, 8);
            s += __shfl_xor(s, 16);
            s += __shfl_xor(s, 32);
            float pn = e / s;
            a0 += z0[m] * pn;
            a1 += z1[m] * pn;
        }
        u0 = a0; u1 = a1;
        if (it < 5) {  // last iteration is NOT normalized
            float ss = u0 * u0 + u1 * u1;
            ss += __shfl_xor(ss, 1); ss += __shfl_xor(ss, 2); ss += __shfl_xor(ss, 4);
            float s = 1.0f / fmaxf(sqrtf(ss), FEPS);
            u0 *= s; u1 *= s;
        }
    }

    *reinterpret_cast<float2*>(out + (size_t)n * DDIM + 2 * lane) = make_float2(u0, u1);
}

extern "C" void kernel_launch(void* const* d_in, const int* in_sizes, int n_in,
                              void* d_out, int out_size, void* d_ws, size_t ws_size,
                              hipStream_t stream) {
    const float* x = (const float*)d_in[0];
    const int* nbr = (const int*)d_in[1];
    float* out = (float*)d_out;

    const size_t inv_bytes = (size_t)NROWS * KC * sizeof(float);
    if (ws_size >= inv_bytes) {
        float* inv = (float*)d_ws;
        capsule_norm_kernel<<<(NROWS * KC + 255) / 256, 256, 0, stream>>>(x, inv);
        routing_kernel<true><<<NROWS / 4, 256, 0, stream>>>(x, nbr, inv, out);
    } else {
        routing_kernel<false><<<NROWS / 4, 256, 0, stream>>>(x, nbr, nullptr, out);
    }
}

// Round 3
// 224.547 us; speedup vs baseline: 3.9888x; 3.9888x over previous
//
#include <hip/hip_runtime.h>
#include <math.h>

// RoutingLayer: N=50000 rows, M=32 neighbors, D=128 = K=8 capsules x 16 dims,
// 6 routing iterations. One wave per row.
//
// Lane mapping (the whole trick): lane = k*8 + j owns ALL 16 dims of capsule k
// for the 4 neighbors m = j, j+8, j+16, j+24.
//   -> dot products (z.u over d) are 16 in-lane FMAs, ZERO shuffles
//   -> capsule norms are in-lane, ZERO shuffles
//   -> softmax over k: shfl_xor 8,16,32 (8 m's in parallel across j-lanes)
//   -> only real reduction: u-partials over the 8 j-lanes (xor 1,2,4)
// |p| <= 1 (dot of unit vectors) so softmax needs no max-subtraction.
// Shuffles with mask 1,2 use DPP quad_perm (fused into v_add at VALU rate);
// mask 8 uses DPP row_ror:8. Masks 4,16,32 stay ds_swizzle/permlane.

constexpr int NROWS = 50000;
constexpr int MN = 32;
constexpr int DDIM = 128;
constexpr float FEPS = 1e-12f;

// DPP cross-lane: quad_perm(1,0,3,2)=xor1 -> 0xB1; quad_perm(2,3,0,1)=xor2 -> 0x4E;
// row_ror:8 = xor8 within a row of 16 -> 0x128.
template <int CTRL>
__device__ __forceinline__ float dpp_mov(float v) {
    int r = __builtin_amdgcn_update_dpp(0, __builtin_bit_cast(int, v), CTRL, 0xF, 0xF, true);
    return __builtin_bit_cast(float, r);
}

// 1/max(sqrt(ss), eps) without a precise divide: rsqrt then one NR step on the
// reciprocal-square-root is overkill for this tolerance -- plain rsqrtf maps to
// v_rsq_f32 (~1 ulp*few), well inside the bf16-derived absmax threshold.
__device__ __forceinline__ float inv_norm(float ss) {
    // ss >= 0; guard the eps case: ss < eps^2 -> clamp to 1/eps behavior.
    float r = rsqrtf(fmaxf(ss, FEPS * FEPS));
    return r;
}

// v / max(||v||, eps) over the 16 in-lane elements (matches torch F.normalize eps).
__device__ __forceinline__ void normalize16(float (&u)[16]) {
    float s0 = 0.f, s1 = 0.f;
#pragma unroll
    for (int d = 0; d < 16; d += 2) {
        s0 = fmaf(u[d], u[d], s0);
        s1 = fmaf(u[d + 1], u[d + 1], s1);
    }
    float iv = inv_norm(s0 + s1);
#pragma unroll
    for (int d = 0; d < 16; ++d) u[d] *= iv;
}

// sum over the 8 j-lanes (lane bits 0..2), result broadcast to all 8.
__device__ __forceinline__ void reduce_bcast_j(float (&u)[16]) {
#pragma unroll
    for (int d = 0; d < 16; ++d) u[d] += dpp_mov<0xB1>(u[d]);   // xor 1 (DPP)
#pragma unroll
    for (int d = 0; d < 16; ++d) u[d] += dpp_mov<0x4E>(u[d]);   // xor 2 (DPP)
#pragma unroll
    for (int d = 0; d < 16; ++d) u[d] += __shfl_xor(u[d], 4);   // xor 4
}

__global__ __launch_bounds__(256, 4) void routing_kernel(const float* __restrict__ x,
                                                         const int* __restrict__ nbr,
                                                         float* __restrict__ out) {
    const int lane = threadIdx.x & 63;
    const int n = blockIdx.x * 4 + (threadIdx.x >> 6);  // 12500*4 = 50000 exactly
    const int j = lane & 7;
    const int k = lane >> 3;

    // ---- own row, capsule k, normalized (in-lane) ----
    float xc[16];
    {
        const float4* p = reinterpret_cast<const float4*>(x + (size_t)n * DDIM + k * 16);
#pragma unroll
        for (int q = 0; q < 4; ++q) {
            float4 v = p[q];
            xc[4 * q + 0] = v.x; xc[4 * q + 1] = v.y;
            xc[4 * q + 2] = v.z; xc[4 * q + 3] = v.w;
        }
        normalize16(xc);
    }

    // ---- gather 4 neighbor capsules (m = j + 8t), normalized in-lane ----
    float z[4][16];
    {
        const int* __restrict__ nrow = nbr + (size_t)n * MN;
        int idx[4];
#pragma unroll
        for (int t = 0; t < 4; ++t) idx[t] = nrow[j + 8 * t];
#pragma unroll
        for (int t = 0; t < 4; ++t) {
            if (idx[t] < NROWS) {
                const float4* p =
                    reinterpret_cast<const float4*>(x + (size_t)idx[t] * DDIM + k * 16);
#pragma unroll
                for (int q = 0; q < 4; ++q) {
                    float4 v = p[q];
                    z[t][4 * q + 0] = v.x; z[t][4 * q + 1] = v.y;
                    z[t][4 * q + 2] = v.z; z[t][4 * q + 3] = v.w;
                }
            } else {  // padding index N -> zero row (stays zero through normalize)
#pragma unroll
                for (int d = 0; d < 16; ++d) z[t][d] = 0.f;
            }
            normalize16(z[t]);
        }
    }

    // ---- iteration 0: p uniform = 1/8 ----
    float u[16];
#pragma unroll
    for (int d = 0; d < 16; ++d)
        u[d] = 0.125f * ((z[0][d] + z[1][d]) + (z[2][d] + z[3][d]));
    reduce_bcast_j(u);
#pragma unroll
    for (int d = 0; d < 16; ++d) u[d] += xc[d];
    normalize16(u);

    // ---- iterations 1..5 ----
#pragma unroll
    for (int it = 1; it < 6; ++it) {
        float pn[4];
#pragma unroll
        for (int t = 0; t < 4; ++t) {
            float a = 0.f, b = 0.f;
#pragma unroll
            for (int d = 0; d < 16; d += 2) {
                a = fmaf(z[t][d], u[d], a);
                b = fmaf(z[t][d + 1], u[d + 1], b);
            }
            float p = a + b;                  // |p| <= 1: unit . unit
            float e = __expf(p);              // no max-subtraction needed
            float s = e + dpp_mov<0x128>(e);  // xor 8 (DPP row_ror:8)
            s += __shfl_xor(s, 16);
            s += __shfl_xor(s, 32);
            pn[t] = e * __frcp_rn(s);
        }
#pragma unroll
        for (int d = 0; d < 16; ++d) {
            float a = z[0][d] * pn[0];
            a = fmaf(z[1][d], pn[1], a);
            a = fmaf(z[2][d], pn[2], a);
            a = fmaf(z[3][d], pn[3], a);
            u[d] = a;
        }
        reduce_bcast_j(u);
#pragma unroll
        for (int d = 0; d < 16; ++d) u[d] += xc[d];
        if (it < 5) normalize16(u);           // last iteration NOT normalized
    }

    // ---- write: lanes j=0..3 of each capsule write one float4 (dims 4j..4j+3) ----
    if (j < 4) {
        float4 w;
        w.x = (j == 0) ? u[0] : (j == 1) ? u[4] : (j == 2) ? u[8]  : u[12];
        w.y = (j == 0) ? u[1] : (j == 1) ? u[5] : (j == 2) ? u[9]  : u[13];
        w.z = (j == 0) ? u[2] : (j == 1) ? u[6] : (j == 2) ? u[10] : u[14];
        w.w = (j == 0) ? u[3] : (j == 1) ? u[7] : (j == 2) ? u[11] : u[15];
        *reinterpret_cast<float4*>(out + (size_t)n * DDIM + k * 16 + 4 * j) = w;
    }
}

extern "C" void kernel_launch(void* const* d_in, const int* in_sizes, int n_in,
                              void* d_out, int out_size, void* d_ws, size_t ws_size,
                              hipStream_t stream) {
    const float* x = (const float*)d_in[0];
    const int* nbr = (const int*)d_in[1];
    float* out = (float*)d_out;
    routing_kernel<<<NROWS / 4, 256, 0, stream>>>(x, nbr, out);
}

// Round 4
// 203.448 us; speedup vs baseline: 4.4025x; 1.1037x over previous
//
#include <hip/hip_runtime.h>
#include <math.h>

// RoutingLayer: N=50000 rows, M=32 neighbors, D=128 = K=8 capsules x 16 dims,
// 6 routing iterations. One wave per row; lane = k*8 + j owns ALL 16 dims of
// capsule k for the 4 neighbors m = j, j+8, j+16, j+24.
//
// VALU-throughput-bound (VALUBusy ~107%, model 160us vs 168us measured), so
// this revision strips VALU ops:
//  - x pre-normalized per-capsule into d_ws by a memory-bound prologue kernel,
//    with a zero row at index N (no bounds check, no inline normalize).
//  - xc/8 folded into the FMA accumulator init (addend of first fma).
//  - u never normalized in-place: dots are scaled by rsqrt(ss)*log2e, exp2
//    used directly (|z.u_hat| <= 1 so no max-subtraction needed: e in [0.37,2.72]).
//  - approx v_rcp/v_rsq/v_exp single-instruction builtins.

constexpr int NROWS = 50000;
constexpr int MN = 32;
constexpr int DDIM = 128;
constexpr float FEPS2 = 1e-24f;  // eps^2, eps = 1e-12 (torch F.normalize)
constexpr float LOG2E = 1.44269504088896340736f;

#if __has_builtin(__builtin_amdgcn_rcpf)
__device__ __forceinline__ float fast_rcp(float v) { return __builtin_amdgcn_rcpf(v); }
#else
__device__ __forceinline__ float fast_rcp(float v) { return __frcp_rn(v); }
#endif
#if __has_builtin(__builtin_amdgcn_rsqf)
__device__ __forceinline__ float fast_rsq(float v) { return __builtin_amdgcn_rsqf(v); }
#else
__device__ __forceinline__ float fast_rsq(float v) { return rsqrtf(v); }
#endif
#if __has_builtin(__builtin_amdgcn_exp2f)
__device__ __forceinline__ float fast_exp2(float v) { return __builtin_amdgcn_exp2f(v); }
#else
__device__ __forceinline__ float fast_exp2(float v) { return exp2f(v); }
#endif

// v + dpp_perm(v): quad_perm(1,0,3,2)=xor1 -> 0xB1; quad_perm(2,3,0,1)=xor2 -> 0x4E;
// row_ror:8 (xor8 within row of 16) -> 0x128. Fuses to a single v_add with DPP.
template <int CTRL>
__device__ __forceinline__ float dpp_add(float v) {
    int r = __builtin_amdgcn_update_dpp(0, __builtin_bit_cast(int, v), CTRL, 0xF, 0xF, true);
    return v + __builtin_bit_cast(float, r);
}

__device__ __forceinline__ void load16(float (&dst)[16], const float* __restrict__ p) {
    const float4* q = reinterpret_cast<const float4*>(p);
#pragma unroll
    for (int i = 0; i < 4; ++i) {
        float4 v = q[i];
        dst[4 * i + 0] = v.x; dst[4 * i + 1] = v.y;
        dst[4 * i + 2] = v.z; dst[4 * i + 3] = v.w;
    }
}

__device__ __forceinline__ void normalize16(float (&v)[16]) {
    float a = v[0] * v[0], b = v[1] * v[1];
#pragma unroll
    for (int d = 2; d < 16; d += 2) {
        a = fmaf(v[d], v[d], a);
        b = fmaf(v[d + 1], v[d + 1], b);
    }
    float iv = fast_rsq(fmaxf(a + b, FEPS2));
#pragma unroll
    for (int d = 0; d < 16; ++d) v[d] *= iv;
}

// sum over the 8 j-lanes (lane bits 0..2), broadcast to all 8.
__device__ __forceinline__ void butterfly8(float (&u)[16]) {
#pragma unroll
    for (int d = 0; d < 16; ++d) u[d] = dpp_add<0xB1>(u[d]);
#pragma unroll
    for (int d = 0; d < 16; ++d) u[d] = dpp_add<0x4E>(u[d]);
#pragma unroll
    for (int d = 0; d < 16; ++d) u[d] += __shfl_xor(u[d], 4);
}

// rsqrt(max(||u||^2, eps^2)) * log2(e) -- the combined dot-scale constant.
__device__ __forceinline__ float inv_norm_log2e(const float (&u)[16]) {
    float a = u[0] * u[0], b = u[1] * u[1];
#pragma unroll
    for (int d = 2; d < 16; d += 2) {
        a = fmaf(u[d], u[d], a);
        b = fmaf(u[d + 1], u[d + 1], b);
    }
    return fast_rsq(fmaxf(a + b, FEPS2)) * LOG2E;
}

// Prologue: per-capsule L2-normalize x into xn[(N+1) x 128]; row N = zeros.
// One float4 per thread; a lane-quad covers one capsule (16 floats).
__global__ __launch_bounds__(256) void norm_kernel(const float* __restrict__ x,
                                                   float* __restrict__ xn) {
    int t = blockIdx.x * 256 + threadIdx.x;
    constexpr int TOTAL = (NROWS + 1) * (DDIM / 4);  // 50001*32, divisible by 4
    if (t >= TOTAL) return;
    int n = t >> 5;
    float4 v = make_float4(0.f, 0.f, 0.f, 0.f);
    if (n < NROWS) v = reinterpret_cast<const float4*>(x)[t];
    float ss = v.x * v.x;
    ss = fmaf(v.y, v.y, ss);
    ss = fmaf(v.z, v.z, ss);
    ss = fmaf(v.w, v.w, ss);
    ss = dpp_add<0xB1>(ss);  // quad (4 threads) = one capsule
    ss = dpp_add<0x4E>(ss);
    float iv = fast_rsq(fmaxf(ss, FEPS2));
    v.x *= iv; v.y *= iv; v.z *= iv; v.w *= iv;
    reinterpret_cast<float4*>(xn)[t] = v;
}

template <bool PRENORM>
__global__ __launch_bounds__(256, 4) void routing_kernel(const float* __restrict__ xsrc,
                                                         const int* __restrict__ nbr,
                                                         float* __restrict__ out) {
    const int lane = threadIdx.x & 63;
    const int n = blockIdx.x * 4 + (threadIdx.x >> 6);  // 12500*4 = 50000
    const int j = lane & 7;
    const int k = lane >> 3;

    // ---- own row capsule, normalized, pre-scaled by 1/8 ----
    float xc8[16];
    load16(xc8, xsrc + n * DDIM + k * 16);
    if (!PRENORM) normalize16(xc8);
#pragma unroll
    for (int d = 0; d < 16; ++d) xc8[d] *= 0.125f;

    // ---- gather 4 neighbor capsules (m = j + 8t) ----
    float z[4][16];
    {
        const int* __restrict__ nrow = nbr + n * MN;
        int idx[4];
#pragma unroll
        for (int t = 0; t < 4; ++t) idx[t] = nrow[j + 8 * t];
#pragma unroll
        for (int t = 0; t < 4; ++t) {
            if (PRENORM) {
                // idx == NROWS hits the zero pad row: no check, no normalize
                load16(z[t], xsrc + idx[t] * DDIM + k * 16);
            } else {
                if (idx[t] < NROWS) {
                    load16(z[t], xsrc + idx[t] * DDIM + k * 16);
                    normalize16(z[t]);
                } else {
#pragma unroll
                    for (int d = 0; d < 16; ++d) z[t][d] = 0.f;
                }
            }
        }
    }

    // ---- iteration 0: p uniform = 1/8; partial = xc/8 + 0.125*sum_t z ----
    float u[16];
#pragma unroll
    for (int d = 0; d < 16; ++d) {
        float a = fmaf(z[0][d], 0.125f, xc8[d]);
        a = fmaf(z[1][d], 0.125f, a);
        a = fmaf(z[2][d], 0.125f, a);
        a = fmaf(z[3][d], 0.125f, a);
        u[d] = a;
    }
    butterfly8(u);
    float c = inv_norm_log2e(u);  // u kept raw; scale folded into dots

    // ---- iterations 1..5 ----
#pragma unroll
    for (int it = 1; it < 6; ++it) {
        float pn[4];
#pragma unroll
        for (int t = 0; t < 4; ++t) {
            float a = z[t][0] * u[0], b = z[t][1] * u[1];
#pragma unroll
            for (int d = 2; d < 16; d += 2) {
                a = fmaf(z[t][d], u[d], a);
                b = fmaf(z[t][d + 1], u[d + 1], b);
            }
            // p_hat = (z . u_raw) * rsqrt(ss); e = exp(p_hat) = exp2(p_hat*log2e)
            float e = fast_exp2((a + b) * c);
            float s = dpp_add<0x128>(e);  // xor 8: sum over capsules (stride-8 lanes)
            s += __shfl_xor(s, 16);
            s += __shfl_xor(s, 32);
            pn[t] = e * fast_rcp(s);
        }
#pragma unroll
        for (int d = 0; d < 16; ++d) {
            float a = fmaf(z[0][d], pn[0], xc8[d]);  // xc/8 folded into addend
            a = fmaf(z[1][d], pn[1], a);
            a = fmaf(z[2][d], pn[2], a);
            a = fmaf(z[3][d], pn[3], a);
            u[d] = a;
        }
        butterfly8(u);
        if (it < 5) c = inv_norm_log2e(u);  // last iteration NOT normalized
    }

    // ---- write: lane j stores dims (2j, 2j+1) of capsule k = out + n*128 + 2*lane.
    // Compile-time-indexed select chain (runtime-indexed u[] would go to scratch).
    float w0 = u[0], w1 = u[1];
#pragma unroll
    for (int d = 1; d < 8; ++d) {
        if (j == d) { w0 = u[2 * d]; w1 = u[2 * d + 1]; }
    }
    *reinterpret_cast<float2*>(out + n * DDIM + 2 * lane) = make_float2(w0, w1);
}

extern "C" void kernel_launch(void* const* d_in, const int* in_sizes, int n_in,
                              void* d_out, int out_size, void* d_ws, size_t ws_size,
                              hipStream_t stream) {
    const float* x = (const float*)d_in[0];
    const int* nbr = (const int*)d_in[1];
    float* out = (float*)d_out;

    const size_t need = (size_t)(NROWS + 1) * DDIM * sizeof(float);
    if (ws_size >= need) {
        float* xn = (float*)d_ws;
        constexpr int TOTAL = (NROWS + 1) * (DDIM / 4);
        norm_kernel<<<(TOTAL + 255) / 256, 256, 0, stream>>>(x, xn);
        routing_kernel<true><<<NROWS / 4, 256, 0, stream>>>(xn, nbr, out);
    } else {
        routing_kernel<false><<<NROWS / 4, 256, 0, stream>>>(x, nbr, out);
    }
}